// Round 10
// baseline (96.888 us; speedup 1.0000x reference)
//
#include <hip/hip_runtime.h>

#define SDIM 500
#define DDIM 64
#define NT   256
#define RSTRIDE 512

__device__ __forceinline__ unsigned ford(float x) {
    unsigned u = __float_as_uint(x);
    return u ^ ((unsigned)((int)u >> 31) | 0x80000000u);
}

__device__ __forceinline__ float dot16(float4 a0, float4 a1, float4 a2, float4 a3,
                                       float4 b0, float4 b1, float4 b2, float4 b3) {
    return a0.x*b0.x + a0.y*b0.y + a0.z*b0.z + a0.w*b0.w
         + a1.x*b1.x + a1.y*b1.y + a1.z*b1.z + a1.w*b1.w
         + a2.x*b2.x + a2.y*b2.y + a2.z*b2.z + a2.w*b2.w
         + a3.x*b3.x + a3.y*b3.y + a3.z*b3.z + a3.w*b3.w;
}

// ---------------- Kernel A: gather + score only (max gather concurrency) ----
__global__ __launch_bounds__(NT) void rs_score(
    const int* __restrict__ need_replace,
    const float* __restrict__ union_feature,
    const float* __restrict__ all_items,
    const int* __restrict__ sample_items,
    const float* __restrict__ Wm,
    const float* __restrict__ bv,
    unsigned* __restrict__ ws_fv,     // (N,512)
    float* __restrict__ ws_key)       // (N,512)
{
    __shared__ __align__(16) float s_uf[128];
    __shared__ __align__(16) float s_uif[DDIM];
    __shared__ unsigned s_fv[SDIM];
    __shared__ float    s_key[SDIM];
    __shared__ int      s_samp[SDIM];

    const int n    = blockIdx.x;
    const int tid  = threadIdx.x;
    const int part = tid & 3, quad = tid >> 2;

    const int user = need_replace[2 * n];
    const int item = need_replace[2 * n + 1];
    const int* samp_row = sample_items + (long)user * SDIM;

    if (tid < 128) s_uf[tid] = union_feature[(long)n * 128 + tid];
    for (int s = tid; s < SDIM; s += NT) s_samp[s] = samp_row[s];
    const float4* ir = (const float4*)(all_items + (long)item * DDIM) + part * 4;
    const float4 wiA = ir[0], wiB = ir[1], wiC = ir[2], wiD = ir[3];
    __syncthreads();

    // uif = W @ uf + b
    {
        const float4* wr4 = (const float4*)(Wm + (long)quad * 128);
        const float4* uf4 = (const float4*)s_uf;
        float acc = 0.f;
        #pragma unroll
        for (int q = 0; q < 8; ++q) {
            float4 w4 = wr4[part + q * 4];
            float4 u4 = uf4[part + q * 4];
            acc += w4.x * u4.x + w4.y * u4.y + w4.z * u4.z + w4.w * u4.w;
        }
        acc += __shfl_xor(acc, 1);
        acc += __shfl_xor(acc, 2);
        if (part == 0) s_uif[quad] = acc + bv[quad];
    }
    __syncthreads();
    const float4* ur = (const float4*)s_uif + part * 4;
    const float4 wuA = ur[0], wuB = ur[1], wuC = ur[2], wuD = ur[3];

    // score loop (depth-1 prefetch, proven neutral-safe)
    float4 f0, f1, f2, f3;
    {
        const float4* p = (const float4*)(all_items + (long)s_samp[quad] * DDIM) + part * 4;
        f0 = p[0]; f1 = p[1]; f2 = p[2]; f3 = p[3];
    }
    #pragma unroll
    for (int i = 0; i < 8; ++i) {
        const int s = i * 64 + quad;
        float4 g0 = f0, g1 = f1, g2 = f2, g3 = f3;
        if (i < 7) {
            const int sn = s + 64;
            const bool actn = (sn < SDIM);
            const int idxn = s_samp[actn ? sn : 0];
            const float4* q = (const float4*)(all_items + (long)idxn * DDIM) + part * 4;
            if (actn) { g0 = q[0]; g1 = q[1]; g2 = q[2]; g3 = q[3]; }
        }
        const bool act = (s < SDIM);
        float a0 = dot16(f0, f1, f2, f3, wiA, wiB, wiC, wiD);
        float a1 = dot16(f0, f1, f2, f3, wuA, wuB, wuC, wuD);
        a0 += __shfl_xor(a0, 1); a0 += __shfl_xor(a0, 2);
        a1 += __shfl_xor(a1, 1); a1 += __shfl_xor(a1, 2);
        if (act && part == 0) { s_fv[s] = ford(a0); s_key[s] = a1; }
        f0 = g0; f1 = g1; f2 = g2; f3 = g3;
    }
    __syncthreads();

    // coalesced dump
    const long rb = (long)n * RSTRIDE;
    for (int s = tid; s < SDIM; s += NT) {
        ws_fv[rb + s]  = s_fv[s];
        ws_key[rb + s] = s_key[s];
    }
}

// ---------------- Kernel B: selection only (LDS/VALU, coalesced loads) ------
__global__ __launch_bounds__(NT) void rs_select(
    const int* __restrict__ need_replace,
    const float* __restrict__ all_items,
    const int* __restrict__ sample_items,
    const float* __restrict__ gumbel_u,
    const unsigned* __restrict__ ws_fv,
    const float* __restrict__ ws_key,
    float* __restrict__ out_items,
    float* __restrict__ out_feat,
    float* __restrict__ ws_sim)
{
    __shared__ unsigned s_fv[SDIM];
    __shared__ float    s_key[SDIM];
    __shared__ int      s_samp[SDIM];
    __shared__ int      s_hist[256];
    __shared__ float    s_mv[4];
    __shared__ int      s_mi[4];
    __shared__ int      s_cnt4[4];
    __shared__ int      s_selb, s_selk, s_k, s_tn;
    __shared__ int      s_tbuf[64];

    const int n    = blockIdx.x;
    const int tid  = threadIdx.x;
    const int wid  = tid >> 6;

    const int user = need_replace[2 * n];
    const int* samp_row = sample_items + (long)user * SDIM;
    const float* gur = gumbel_u + (long)n * SDIM;
    const long rb = (long)n * RSTRIDE;

    for (int s = tid; s < SDIM; s += NT) {
        s_fv[s]   = ws_fv[rb + s];
        s_key[s]  = ws_key[rb + s];
        s_samp[s] = samp_row[s];
    }
    __syncthreads();

    // argmax of replace_score + gumbel (first-max tie-break)
    {
        float bvv = -__builtin_inff();
        int   bii = SDIM;
        for (int s = tid; s < SDIM; s += NT) {
            float u = gur[s];
            float g = -logf(-logf(u * (1.0f - 2e-7f) + 1e-7f));
            float v = s_key[s] + g;
            if (v > bvv) { bvv = v; bii = s; }
        }
        #pragma unroll
        for (int off = 1; off < 64; off <<= 1) {
            float v2 = __shfl_xor(bvv, off); int i2 = __shfl_xor(bii, off);
            if (v2 > bvv || (v2 == bvv && i2 < bii)) { bvv = v2; bii = i2; }
        }
        if ((tid & 63) == 0) { s_mv[wid] = bvv; s_mi[wid] = bii; }
        __syncthreads();
        if (tid == 0) {
            float mv = s_mv[0]; int mi = s_mi[0];
            #pragma unroll
            for (int w = 1; w < 4; ++w) {
                float v2 = s_mv[w]; int i2 = s_mi[w];
                if (v2 > mv || (v2 == mv && i2 < mi)) { mv = v2; mi = i2; }
            }
            s_k = mi;
        }
        __syncthreads();
    }
    const int k = s_k;

    // feature output
    {
        const int src = s_samp[k];
        if (tid < DDIM)
            out_feat[(long)n * DDIM + tid] = all_items[(long)src * DDIM + tid];
    }

    // rank_k
    int rank_k;
    {
        const unsigned fvk = s_fv[k];
        int cnt = 0;
        for (int s = tid; s < SDIM; s += NT) {
            unsigned v = s_fv[s];
            cnt += (int)((v < fvk) | ((v == fvk) & (s < k)));
        }
        #pragma unroll
        for (int off = 1; off < 64; off <<= 1) cnt += __shfl_xor(cnt, off);
        if ((tid & 63) == 0) s_cnt4[wid] = cnt;
        __syncthreads();
        rank_k = s_cnt4[0] + s_cnt4[1] + s_cnt4[2] + s_cnt4[3];
    }

    // radix-select
    unsigned prefix = 0;
    int krem = k;
    for (int pass = 0; pass < 4; ++pass) {
        const int shift = 24 - 8 * pass;
        s_hist[tid] = 0;
        __syncthreads();
        const unsigned himask = pass ? (0xFFFFFFFFu << (shift + 8)) : 0u;
        for (int s = tid; s < SDIM; s += NT) {
            unsigned v = s_fv[s];
            if ((v & himask) == prefix) atomicAdd(&s_hist[(v >> shift) & 0xFF], 1);
        }
        __syncthreads();
        if (tid < 64) {
            int h0 = s_hist[4*tid], h1 = s_hist[4*tid+1], h2 = s_hist[4*tid+2], h3 = s_hist[4*tid+3];
            int s4 = h0 + h1 + h2 + h3, inc = s4;
            #pragma unroll
            for (int off = 1; off < 64; off <<= 1) {
                int t = __shfl_up(inc, off);
                if (tid >= off) inc += t;
            }
            int base = inc - s4;
            if (krem >= base && krem < inc) {
                if      (krem < base + h0)           { s_selb = 4*tid;   s_selk = krem - base; }
                else if (krem < base + h0 + h1)      { s_selb = 4*tid+1; s_selk = krem - base - h0; }
                else if (krem < base + h0 + h1 + h2) { s_selb = 4*tid+2; s_selk = krem - base - h0 - h1; }
                else                                 { s_selb = 4*tid+3; s_selk = krem - base - h0 - h1 - h2; }
            }
        }
        __syncthreads();
        prefix |= ((unsigned)s_selb) << shift;
        krem = s_selk;
        if (pass == 0) { if (tid == 0) s_tn = 0; }
    }

    // stable tie resolution
    __syncthreads();
    for (int s = tid; s < SDIM; s += NT) {
        if (s_fv[s] == prefix) {
            int slot = atomicAdd(&s_tn, 1);
            if (slot < 64) s_tbuf[slot] = s;
        }
    }
    __syncthreads();
    if (tid == 0) {
        int ntie = s_tn;
        int js = s_tbuf[0];
        if (ntie > 1) {
            for (int a = 0; a < ntie; ++a) {
                int c = s_tbuf[a], r = 0;
                for (int b2 = 0; b2 < ntie; ++b2) r += (int)(s_tbuf[b2] < c);
                if (r == krem) js = c;
            }
        }
        out_items[n] = (float)s_samp[js];
        ws_sim[n]    = (float)(rank_k + 1) / (float)SDIM;
    }
}

// ---------------- fallback: verbatim round-9 monolith (81.5 us) -------------
__global__ __launch_bounds__(NT) void rs_mono(
    const int* __restrict__ need_replace,
    const float* __restrict__ union_feature,
    const float* __restrict__ all_items,
    const int* __restrict__ sample_items,
    const float* __restrict__ Wm,
    const float* __restrict__ bv,
    const float* __restrict__ gumbel_u,
    float* __restrict__ out_items,
    float* __restrict__ out_feat,
    float* __restrict__ ws_sim)
{
    __shared__ __align__(16) float s_uf[128];
    __shared__ __align__(16) float s_uif[DDIM];
    __shared__ unsigned s_fv[SDIM];
    __shared__ float    s_key[SDIM];
    __shared__ int      s_samp[SDIM];
    __shared__ int      s_hist[256];
    __shared__ float    s_mv[4];
    __shared__ int      s_mi[4];
    __shared__ int      s_cnt4[4];
    __shared__ int      s_selb, s_selk, s_k, s_tn;
    __shared__ int      s_tbuf[64];

    const int n    = blockIdx.x;
    const int tid  = threadIdx.x;
    const int wid  = tid >> 6;
    const int part = tid & 3, quad = tid >> 2;

    const int user = need_replace[2 * n];
    const int item = need_replace[2 * n + 1];
    const int*   samp_row = sample_items + (long)user * SDIM;
    const float* gur      = gumbel_u + (long)n * SDIM;

    if (tid < 128) s_uf[tid] = union_feature[(long)n * 128 + tid];
    for (int s = tid; s < SDIM; s += NT) s_samp[s] = samp_row[s];
    const float4* ir = (const float4*)(all_items + (long)item * DDIM) + part * 4;
    const float4 wiA = ir[0], wiB = ir[1], wiC = ir[2], wiD = ir[3];
    __syncthreads();

    {
        const float4* wr4 = (const float4*)(Wm + (long)quad * 128);
        const float4* uf4 = (const float4*)s_uf;
        float acc = 0.f;
        #pragma unroll
        for (int q = 0; q < 8; ++q) {
            float4 w4 = wr4[part + q * 4];
            float4 u4 = uf4[part + q * 4];
            acc += w4.x * u4.x + w4.y * u4.y + w4.z * u4.z + w4.w * u4.w;
        }
        acc += __shfl_xor(acc, 1);
        acc += __shfl_xor(acc, 2);
        if (part == 0) s_uif[quad] = acc + bv[quad];
    }
    __syncthreads();
    const float4* ur = (const float4*)s_uif + part * 4;
    const float4 wuA = ur[0], wuB = ur[1], wuC = ur[2], wuD = ur[3];

    float4 f0, f1, f2, f3;
    {
        const float4* p = (const float4*)(all_items + (long)s_samp[quad] * DDIM) + part * 4;
        f0 = p[0]; f1 = p[1]; f2 = p[2]; f3 = p[3];
    }
    #pragma unroll
    for (int i = 0; i < 8; ++i) {
        const int s = i * 64 + quad;
        float4 g0 = f0, g1 = f1, g2 = f2, g3 = f3;
        if (i < 7) {
            const int sn = s + 64;
            const bool actn = (sn < SDIM);
            const int idxn = s_samp[actn ? sn : 0];
            const float4* q = (const float4*)(all_items + (long)idxn * DDIM) + part * 4;
            if (actn) { g0 = q[0]; g1 = q[1]; g2 = q[2]; g3 = q[3]; }
        }
        const bool act = (s < SDIM);
        float a0 = dot16(f0, f1, f2, f3, wiA, wiB, wiC, wiD);
        float a1 = dot16(f0, f1, f2, f3, wuA, wuB, wuC, wuD);
        a0 += __shfl_xor(a0, 1); a0 += __shfl_xor(a0, 2);
        a1 += __shfl_xor(a1, 1); a1 += __shfl_xor(a1, 2);
        if (act && part == 0) { s_fv[s] = ford(a0); s_key[s] = a1; }
        f0 = g0; f1 = g1; f2 = g2; f3 = g3;
    }
    __syncthreads();

    {
        float bvv = -__builtin_inff();
        int   bii = SDIM;
        for (int s = tid; s < SDIM; s += NT) {
            float u = gur[s];
            float g = -logf(-logf(u * (1.0f - 2e-7f) + 1e-7f));
            float v = s_key[s] + g;
            if (v > bvv) { bvv = v; bii = s; }
        }
        #pragma unroll
        for (int off = 1; off < 64; off <<= 1) {
            float v2 = __shfl_xor(bvv, off); int i2 = __shfl_xor(bii, off);
            if (v2 > bvv || (v2 == bvv && i2 < bii)) { bvv = v2; bii = i2; }
        }
        if ((tid & 63) == 0) { s_mv[wid] = bvv; s_mi[wid] = bii; }
        __syncthreads();
        if (tid == 0) {
            float mv = s_mv[0]; int mi = s_mi[0];
            #pragma unroll
            for (int w = 1; w < 4; ++w) {
                float v2 = s_mv[w]; int i2 = s_mi[w];
                if (v2 > mv || (v2 == mv && i2 < mi)) { mv = v2; mi = i2; }
            }
            s_k = mi;
        }
        __syncthreads();
    }
    const int k = s_k;

    {
        const int src = s_samp[k];
        if (tid < DDIM)
            out_feat[(long)n * DDIM + tid] = all_items[(long)src * DDIM + tid];
    }

    int rank_k;
    {
        const unsigned fvk = s_fv[k];
        int cnt = 0;
        for (int s = tid; s < SDIM; s += NT) {
            unsigned v = s_fv[s];
            cnt += (int)((v < fvk) | ((v == fvk) & (s < k)));
        }
        #pragma unroll
        for (int off = 1; off < 64; off <<= 1) cnt += __shfl_xor(cnt, off);
        if ((tid & 63) == 0) s_cnt4[wid] = cnt;
        __syncthreads();
        rank_k = s_cnt4[0] + s_cnt4[1] + s_cnt4[2] + s_cnt4[3];
    }

    unsigned prefix = 0;
    int krem = k;
    for (int pass = 0; pass < 4; ++pass) {
        const int shift = 24 - 8 * pass;
        s_hist[tid] = 0;
        __syncthreads();
        const unsigned himask = pass ? (0xFFFFFFFFu << (shift + 8)) : 0u;
        for (int s = tid; s < SDIM; s += NT) {
            unsigned v = s_fv[s];
            if ((v & himask) == prefix) atomicAdd(&s_hist[(v >> shift) & 0xFF], 1);
        }
        __syncthreads();
        if (tid < 64) {
            int h0 = s_hist[4*tid], h1 = s_hist[4*tid+1], h2 = s_hist[4*tid+2], h3 = s_hist[4*tid+3];
            int s4 = h0 + h1 + h2 + h3, inc = s4;
            #pragma unroll
            for (int off = 1; off < 64; off <<= 1) {
                int t = __shfl_up(inc, off);
                if (tid >= off) inc += t;
            }
            int base = inc - s4;
            if (krem >= base && krem < inc) {
                if      (krem < base + h0)           { s_selb = 4*tid;   s_selk = krem - base; }
                else if (krem < base + h0 + h1)      { s_selb = 4*tid+1; s_selk = krem - base - h0; }
                else if (krem < base + h0 + h1 + h2) { s_selb = 4*tid+2; s_selk = krem - base - h0 - h1; }
                else                                 { s_selb = 4*tid+3; s_selk = krem - base - h0 - h1 - h2; }
            }
        }
        __syncthreads();
        prefix |= ((unsigned)s_selb) << shift;
        krem = s_selk;
        if (pass == 0) { if (tid == 0) s_tn = 0; }
    }

    __syncthreads();
    for (int s = tid; s < SDIM; s += NT) {
        if (s_fv[s] == prefix) {
            int slot = atomicAdd(&s_tn, 1);
            if (slot < 64) s_tbuf[slot] = s;
        }
    }
    __syncthreads();
    if (tid == 0) {
        int ntie = s_tn;
        int js = s_tbuf[0];
        if (ntie > 1) {
            for (int a = 0; a < ntie; ++a) {
                int c = s_tbuf[a], r = 0;
                for (int b2 = 0; b2 < ntie; ++b2) r += (int)(s_tbuf[b2] < c);
                if (r == krem) js = c;
            }
        }
        out_items[n] = (float)s_samp[js];
        ws_sim[n]    = (float)(rank_k + 1) / (float)SDIM;
    }
}

__global__ __launch_bounds__(NT) void rs_reduce(
    const float* __restrict__ ws_sim, float* __restrict__ out_scal, int N)
{
    __shared__ float s0[NT], s1[NT];
    int tid = threadIdx.x;
    float a = 0.f, m = 0.f;
    for (int i = tid; i < N; i += NT) {
        float sim = ws_sim[i];
        a += fabsf(sim - 0.5f);
        m += sim;
    }
    s0[tid] = a; s1[tid] = m;
    __syncthreads();
    for (int off = NT / 2; off > 0; off >>= 1) {
        if (tid < off) { s0[tid] += s0[tid + off]; s1[tid] += s1[tid + off]; }
        __syncthreads();
    }
    if (tid == 0) {
        out_scal[0] = s0[0] / (float)N;  // similarity_loss
        out_scal[1] = s1[0] / (float)N;  // mean(similarity)
    }
}

extern "C" void kernel_launch(void* const* d_in, const int* in_sizes, int n_in,
                              void* d_out, int out_size, void* d_ws, size_t ws_size,
                              hipStream_t stream) {
    const int*   need_replace  = (const int*)d_in[0];
    const float* union_feature = (const float*)d_in[1];
    const float* all_items     = (const float*)d_in[2];
    const int*   sample_items  = (const int*)d_in[3];
    const float* Wm            = (const float*)d_in[4];
    const float* bv            = (const float*)d_in[5];
    const float* gumbel_u      = (const float*)d_in[6];

    const int N = in_sizes[0] / 2;  // 4096

    float* out       = (float*)d_out;
    float* out_items = out;                       // N
    float* out_feat  = out + N;                   // N*64
    float* out_scal  = out + N + (long)N * DDIM;  // 2 scalars

    const size_t fv_bytes  = (size_t)N * RSTRIDE * sizeof(unsigned);
    const size_t key_bytes = (size_t)N * RSTRIDE * sizeof(float);
    const size_t need      = fv_bytes + key_bytes + (size_t)N * sizeof(float);

    if (ws_size >= need) {
        unsigned* ws_fv  = (unsigned*)d_ws;
        float*    ws_key = (float*)((char*)d_ws + fv_bytes);
        float*    ws_sim = (float*)((char*)d_ws + fv_bytes + key_bytes);
        rs_score<<<N, NT, 0, stream>>>(need_replace, union_feature, all_items,
                                       sample_items, Wm, bv, ws_fv, ws_key);
        rs_select<<<N, NT, 0, stream>>>(need_replace, all_items, sample_items,
                                        gumbel_u, ws_fv, ws_key,
                                        out_items, out_feat, ws_sim);
        rs_reduce<<<1, NT, 0, stream>>>(ws_sim, out_scal, N);
    } else {
        float* ws_sim = (float*)d_ws;
        rs_mono<<<N, NT, 0, stream>>>(need_replace, union_feature, all_items,
                                      sample_items, Wm, bv, gumbel_u,
                                      out_items, out_feat, ws_sim);
        rs_reduce<<<1, NT, 0, stream>>>(ws_sim, out_scal, N);
    }
}

// Round 11
// 81.916 us; speedup vs baseline: 1.1828x; 1.1828x over previous
//
#include <hip/hip_runtime.h>

#define SDIM 500
#define DDIM 64
#define NT   256

__device__ __forceinline__ unsigned ford(float x) {
    unsigned u = __float_as_uint(x);
    return u ^ ((unsigned)((int)u >> 31) | 0x80000000u);
}

__device__ __forceinline__ float dot16(float4 a0, float4 a1, float4 a2, float4 a3,
                                       float4 b0, float4 b1, float4 b2, float4 b3) {
    return a0.x*b0.x + a0.y*b0.y + a0.z*b0.z + a0.w*b0.w
         + a1.x*b1.x + a1.y*b1.y + a1.z*b1.z + a1.w*b1.w
         + a2.x*b2.x + a2.y*b2.y + a2.z*b2.z + a2.w*b2.w
         + a3.x*b3.x + a3.y*b3.y + a3.z*b3.z + a3.w*b3.w;
}

// Round-9 monolith (81.5 us proven) + ONE lever: quad-contiguous gather
// addressing. Lane `part` reads float4s [part, 4+part, 8+part, 12+part] of
// each 256B row, so one load instruction's quad covers a contiguous 64B
// granule (1 request) instead of four 16B requests 64B apart. 4x fewer
// TA/TCP address granules for identical bytes/lines.
__global__ __launch_bounds__(NT) void rs_main(
    const int* __restrict__ need_replace,    // (N,2)
    const float* __restrict__ union_feature, // (N,128)
    const float* __restrict__ all_items,     // (n_items,64)
    const int* __restrict__ sample_items,    // (n_users,500)
    const float* __restrict__ Wm,            // (64,128)
    const float* __restrict__ bv,            // (64)
    const float* __restrict__ gumbel_u,      // (N,500)
    float* __restrict__ out_items,           // (N)
    float* __restrict__ out_feat,            // (N,64)
    float* __restrict__ ws_sim)              // (N)
{
    __shared__ __align__(16) float s_uf[128];
    __shared__ __align__(16) float s_uif[DDIM];
    __shared__ unsigned s_fv[SDIM];   // order-preserving uint of rank_score
    __shared__ float    s_key[SDIM];  // replace_score (raw, pre-gumbel)
    __shared__ int      s_samp[SDIM];
    __shared__ int      s_hist[256];
    __shared__ float    s_mv[4];
    __shared__ int      s_mi[4];
    __shared__ int      s_cnt4[4];
    __shared__ int      s_selb, s_selk, s_k, s_tn;
    __shared__ int      s_tbuf[64];

    const int n    = blockIdx.x;
    const int tid  = threadIdx.x;
    const int wid  = tid >> 6;
    const int part = tid & 3, quad = tid >> 2;

    const int user = need_replace[2 * n];
    const int item = need_replace[2 * n + 1];
    const int*   samp_row = sample_items + (long)user * SDIM;
    const float* gur      = gumbel_u + (long)n * SDIM;

    // ---- stage (coalesced) ----
    if (tid < 128) s_uf[tid] = union_feature[(long)n * 128 + tid];
    for (int s = tid; s < SDIM; s += NT) s_samp[s] = samp_row[s];
    // item-embedding fragment, quad-contiguous layout: lane part owns
    // float4s {part, 4+part, 8+part, 12+part} of the row
    const float4* irb = (const float4*)(all_items + (long)item * DDIM);
    const float4 wiA = irb[part], wiB = irb[part + 4], wiC = irb[part + 8], wiD = irb[part + 12];
    __syncthreads();

    // ---- uif = W @ uf + b : 4 lanes per output row (already quad-contiguous) ----
    {
        const float4* wr4 = (const float4*)(Wm + (long)quad * 128);
        const float4* uf4 = (const float4*)s_uf;
        float acc = 0.f;
        #pragma unroll
        for (int q = 0; q < 8; ++q) {
            float4 w4 = wr4[part + q * 4];
            float4 u4 = uf4[part + q * 4];
            acc += w4.x * u4.x + w4.y * u4.y + w4.z * u4.z + w4.w * u4.w;
        }
        acc += __shfl_xor(acc, 1);
        acc += __shfl_xor(acc, 2);
        if (part == 0) s_uif[quad] = acc + bv[quad];
    }
    __syncthreads();
    const float4* urb = (const float4*)s_uif;
    const float4 wuA = urb[part], wuB = urb[part + 4], wuC = urb[part + 8], wuD = urb[part + 12];

    // ---- score phase: quad per sample row, quad-contiguous gathers,
    //      depth-1 prefetch ----
    float4 f0, f1, f2, f3;
    {
        const float4* p = (const float4*)(all_items + (long)s_samp[quad] * DDIM);
        f0 = p[part]; f1 = p[part + 4]; f2 = p[part + 8]; f3 = p[part + 12];
    }
    #pragma unroll
    for (int i = 0; i < 8; ++i) {
        const int s = i * 64 + quad;
        float4 g0 = f0, g1 = f1, g2 = f2, g3 = f3;
        if (i < 7) {
            const int sn = s + 64;
            const bool actn = (sn < SDIM);
            const int idxn = s_samp[actn ? sn : 0];
            const float4* q = (const float4*)(all_items + (long)idxn * DDIM);
            if (actn) { g0 = q[part]; g1 = q[part + 4]; g2 = q[part + 8]; g3 = q[part + 12]; }
        }
        const bool act = (s < SDIM);
        float a0 = dot16(f0, f1, f2, f3, wiA, wiB, wiC, wiD);
        float a1 = dot16(f0, f1, f2, f3, wuA, wuB, wuC, wuD);
        a0 += __shfl_xor(a0, 1); a0 += __shfl_xor(a0, 2);
        a1 += __shfl_xor(a1, 1); a1 += __shfl_xor(a1, 2);
        if (act && part == 0) { s_fv[s] = ford(a0); s_key[s] = a1; }
        f0 = g0; f1 = g1; f2 = g2; f3 = g3;
    }
    __syncthreads();

    // ---- argmax of replace_score + gumbel (first-max tie-break) ----
    {
        float bvv = -__builtin_inff();
        int   bii = SDIM;
        for (int s = tid; s < SDIM; s += NT) {
            float u = gur[s];
            float g = -logf(-logf(u * (1.0f - 2e-7f) + 1e-7f));
            float v = s_key[s] + g;
            if (v > bvv) { bvv = v; bii = s; }
        }
        #pragma unroll
        for (int off = 1; off < 64; off <<= 1) {
            float v2 = __shfl_xor(bvv, off); int i2 = __shfl_xor(bii, off);
            if (v2 > bvv || (v2 == bvv && i2 < bii)) { bvv = v2; bii = i2; }
        }
        if ((tid & 63) == 0) { s_mv[wid] = bvv; s_mi[wid] = bii; }
        __syncthreads();
        if (tid == 0) {
            float mv = s_mv[0]; int mi = s_mi[0];
            #pragma unroll
            for (int w = 1; w < 4; ++w) {
                float v2 = s_mv[w]; int i2 = s_mi[w];
                if (v2 > mv || (v2 == mv && i2 < mi)) { mv = v2; mi = i2; }
            }
            s_k = mi;
        }
        __syncthreads();
    }
    const int k = s_k;

    // ---- overlap: feature output = all_items[samp[k]] ----
    {
        const int src = s_samp[k];
        if (tid < DDIM)
            out_feat[(long)n * DDIM + tid] = all_items[(long)src * DDIM + tid];
    }

    // ---- rank_k = stable rank of element k ----
    int rank_k;
    {
        const unsigned fvk = s_fv[k];
        int cnt = 0;
        for (int s = tid; s < SDIM; s += NT) {
            unsigned v = s_fv[s];
            cnt += (int)((v < fvk) | ((v == fvk) & (s < k)));
        }
        #pragma unroll
        for (int off = 1; off < 64; off <<= 1) cnt += __shfl_xor(cnt, off);
        if ((tid & 63) == 0) s_cnt4[wid] = cnt;
        __syncthreads();
        rank_k = s_cnt4[0] + s_cnt4[1] + s_cnt4[2] + s_cnt4[3];
    }

    // ---- radix-select: j* = index of k-th smallest (stable) ----
    unsigned prefix = 0;
    int krem = k;
    for (int pass = 0; pass < 4; ++pass) {
        const int shift = 24 - 8 * pass;
        s_hist[tid] = 0;
        __syncthreads();
        const unsigned himask = pass ? (0xFFFFFFFFu << (shift + 8)) : 0u;
        for (int s = tid; s < SDIM; s += NT) {
            unsigned v = s_fv[s];
            if ((v & himask) == prefix) atomicAdd(&s_hist[(v >> shift) & 0xFF], 1);
        }
        __syncthreads();
        if (tid < 64) {
            int h0 = s_hist[4*tid], h1 = s_hist[4*tid+1], h2 = s_hist[4*tid+2], h3 = s_hist[4*tid+3];
            int s4 = h0 + h1 + h2 + h3, inc = s4;
            #pragma unroll
            for (int off = 1; off < 64; off <<= 1) {
                int t = __shfl_up(inc, off);
                if (tid >= off) inc += t;
            }
            int base = inc - s4;
            if (krem >= base && krem < inc) {
                if      (krem < base + h0)           { s_selb = 4*tid;   s_selk = krem - base; }
                else if (krem < base + h0 + h1)      { s_selb = 4*tid+1; s_selk = krem - base - h0; }
                else if (krem < base + h0 + h1 + h2) { s_selb = 4*tid+2; s_selk = krem - base - h0 - h1; }
                else                                 { s_selb = 4*tid+3; s_selk = krem - base - h0 - h1 - h2; }
            }
        }
        __syncthreads();
        prefix |= ((unsigned)s_selb) << shift;
        krem = s_selk;
        if (pass == 0) { if (tid == 0) s_tn = 0; }
    }

    // ---- resolve ties (equal fv) by original index: stable order ----
    __syncthreads();
    for (int s = tid; s < SDIM; s += NT) {
        if (s_fv[s] == prefix) {
            int slot = atomicAdd(&s_tn, 1);
            if (slot < 64) s_tbuf[slot] = s;
        }
    }
    __syncthreads();
    if (tid == 0) {
        int ntie = s_tn;
        int js = s_tbuf[0];
        if (ntie > 1) {
            for (int a = 0; a < ntie; ++a) {
                int c = s_tbuf[a], r = 0;
                for (int b2 = 0; b2 < ntie; ++b2) r += (int)(s_tbuf[b2] < c);
                if (r == krem) js = c;
            }
        }
        out_items[n] = (float)s_samp[js];
        ws_sim[n]    = (float)(rank_k + 1) / (float)SDIM;
    }
}

__global__ __launch_bounds__(NT) void rs_reduce(
    const float* __restrict__ ws_sim, float* __restrict__ out_scal, int N)
{
    __shared__ float s0[NT], s1[NT];
    int tid = threadIdx.x;
    float a = 0.f, m = 0.f;
    for (int i = tid; i < N; i += NT) {
        float sim = ws_sim[i];
        a += fabsf(sim - 0.5f);
        m += sim;
    }
    s0[tid] = a; s1[tid] = m;
    __syncthreads();
    for (int off = NT / 2; off > 0; off >>= 1) {
        if (tid < off) { s0[tid] += s0[tid + off]; s1[tid] += s1[tid + off]; }
        __syncthreads();
    }
    if (tid == 0) {
        out_scal[0] = s0[0] / (float)N;  // similarity_loss
        out_scal[1] = s1[0] / (float)N;  // mean(similarity)
    }
}

extern "C" void kernel_launch(void* const* d_in, const int* in_sizes, int n_in,
                              void* d_out, int out_size, void* d_ws, size_t ws_size,
                              hipStream_t stream) {
    const int*   need_replace  = (const int*)d_in[0];
    const float* union_feature = (const float*)d_in[1];
    const float* all_items     = (const float*)d_in[2];
    const int*   sample_items  = (const int*)d_in[3];
    const float* Wm            = (const float*)d_in[4];
    const float* bv            = (const float*)d_in[5];
    const float* gumbel_u      = (const float*)d_in[6];

    const int N = in_sizes[0] / 2;  // 4096

    float* out       = (float*)d_out;
    float* out_items = out;                       // N
    float* out_feat  = out + N;                   // N*64
    float* out_scal  = out + N + (long)N * DDIM;  // 2 scalars
    float* ws_sim    = (float*)d_ws;              // N floats

    rs_main<<<N, NT, 0, stream>>>(need_replace, union_feature, all_items,
                                  sample_items, Wm, bv, gumbel_u,
                                  out_items, out_feat, ws_sim);
    rs_reduce<<<1, NT, 0, stream>>>(ws_sim, out_scal, N);
}